// Round 9
// baseline (260.623 us; speedup 1.0000x reference)
//
#include <hip/hip_runtime.h>
#include <hip/hip_bf16.h>

#define NB   4
#define MD   2048
#define KD   2048
#define ND   2048

// fallback (fused) kernel tile
#define BM   128
#define BN   128

typedef short bf16x8 __attribute__((ext_vector_type(8)));
typedef float f32x4  __attribute__((ext_vector_type(4)));
typedef float f32x16 __attribute__((ext_vector_type(16)));
typedef unsigned int u32;

#define MFMA16(a, b, c) __builtin_amdgcn_mfma_f32_16x16x32_bf16(a, b, c, 0, 0, 0)
#define MFMA32(a, b, c) __builtin_amdgcn_mfma_f32_32x32x16_bf16(a, b, c, 0, 0, 0)
#define BAR()    __builtin_amdgcn_s_barrier()
#define PRIO(n)  __builtin_amdgcn_s_setprio(n)
#define WAITV(n) asm volatile("s_waitcnt vmcnt(" #n ")" ::: "memory")
#define SCHEDB() __builtin_amdgcn_sched_barrier(0)

// pack two fp32 -> one dword of 2 bf16 (RNE)
__device__ __forceinline__ unsigned pk2(float lo, float hi) {
    union { __hip_bfloat162 h2; unsigned u; } c;
    c.h2 = __float22bfloat162_rn(make_float2(lo, hi));
    return c.u;
}

__device__ __forceinline__ void gload_lds16(const void* g, void* l) {
    __builtin_amdgcn_global_load_lds(
        (const __attribute__((address_space(1))) u32*)g,
        (__attribute__((address_space(3))) u32*)l,
        16, 0, 0);
}

// ---- Phase 1 (fused): A fp32->bf16 cast (8 elem/thread)  +  B -> BT bf16 ----
#define NCAST ((NB * MD * KD / 8) / 256)   // 8192 cast blocks (uint4 out/thread)

__global__ __launch_bounds__(256) void prep_kernel(
    const float* __restrict__ A, const float* __restrict__ B,
    unsigned short* __restrict__ Abf, unsigned short* __restrict__ BT)
{
    __shared__ float t[64][65];   // transpose tile; +1 pad -> <=2-way conflicts (free)
    const int tid = threadIdx.x;

    if (blockIdx.x < NCAST) {
        const size_t idx = (size_t)blockIdx.x * 256 + tid;   // uint4 (8 bf16) index
        const float4 v0 = ((const float4*)A)[2 * idx];
        const float4 v1 = ((const float4*)A)[2 * idx + 1];
        uint4 w;
        w.x = pk2(v0.x, v0.y); w.y = pk2(v0.z, v0.w);
        w.z = pk2(v1.x, v1.y); w.w = pk2(v1.z, v1.w);
        ((uint4*)Abf)[idx] = w;
        return;
    }
    const int bx  = blockIdx.x - NCAST;      // 0..4095
    const int b   = bx >> 10;                // batch (1024 tiles per batch)
    const int rem = bx & 1023;
    const int k0  = (rem & 31) * 64;
    const int n0  = (rem >> 5) * 64;

    const float* Bb = B + (size_t)b * KD * ND;
    const int rk = tid >> 4;                 // 0..15, +16/pass
    const int rn = (tid & 15) * 4;
    #pragma unroll
    for (int p = 0; p < 4; ++p) {
        const int kl = p * 16 + rk;
        const float4 v = *(const float4*)(Bb + (size_t)(k0 + kl) * ND + n0 + rn);
        t[kl][rn + 0] = v.x; t[kl][rn + 1] = v.y;
        t[kl][rn + 2] = v.z; t[kl][rn + 3] = v.w;
    }
    __syncthreads();
    const int wn = tid >> 2;                 // 0..63 (owns column n)
    const int wk = (tid & 3) * 16;           // 16 consecutive k
    float f[16];
    #pragma unroll
    for (int j = 0; j < 16; ++j) f[j] = t[wk + j][wn];
    uint4 w0, w1;
    w0.x = pk2(f[0], f[1]);   w0.y = pk2(f[2], f[3]);
    w0.z = pk2(f[4], f[5]);   w0.w = pk2(f[6], f[7]);
    w1.x = pk2(f[8], f[9]);   w1.y = pk2(f[10], f[11]);
    w1.z = pk2(f[12], f[13]); w1.w = pk2(f[14], f[15]);
    unsigned short* dst = BT + (size_t)b * ND * KD + (size_t)(n0 + wn) * KD + k0 + wk;
    *(uint4*)(dst) = w0;
    *(uint4*)(dst + 8) = w1;
}

// ---------------------------------------------------------------------------
// Phase 2 (round 9): 256x256 tile, BK=64, 8 waves (2M x 4N), 32x32x16 MFMA,
// FRAGMENT-MAJOR LDS layout (conflict-free by construction).
//
// R8 post-mortem: row-major [row][64] + 32x32 reads -> slot index constant
// per 32-lane half -> 4 rows share each bank group -> 6.29M conflict-cycles
// (= the whole 63->73 µs regression; no XOR fix exists at this geometry).
// R9: store tiles in READ order: byte = blk*4096 + ks*1024 + lane*16
// (blk = 32-row block, ks = 16-k slice, lane = hi*32+l31). Every frag read
// is then uniform_base + lane*16: consecutive lanes -> consecutive 16 B ->
// ZERO conflicts, and all block/ks offsets fold into 16-bit ds_read
// immediates (one address VGPR). Staging keeps a linear LDS dest (tid*16,
// rule #21); the global SOURCE is re-indexed: thread tid, round rr loads
// row = rr*64 + (tid>>8)*32 + (tid&31), k = ((tid>>6)&3)*16 + ((tid>>5)&1)*8
// (16 B contiguous). Fragment content per lane identical to R8 (verified
// correct); only the storage permutation changed, consistently on both
// sides. Phase structure, race ledger, epilogue: unchanged from R8.
// ---------------------------------------------------------------------------

// Stage one full 256x64 tile (32 KB): 4 rounds x 512 thr x 16 B.
#define STAGE4(dst, buf, base, tile) do {                                    \
    _Pragma("unroll")                                                        \
    for (int rr_ = 0; rr_ < 4; ++rr_) {                                      \
        gload_lds16((base) + (size_t)(rr_ * 64 + sRowB) * KD                 \
                           + (size_t)(tile) * 64 + sK,                       \
                    &dst[buf][0] + rr_ * 4096 + tid * 8);                    \
    }                                                                        \
} while (0)

#define NOSTG ((void)0)

// one K=64 tile (buffer p): reads -> MFMA ks01 -> reads -> STG -> MFMA ks23
#define PHASE(p, STG) do {                                                   \
    WAITV(0); BAR();                                                         \
    const char* Ab_ = ldsA + (p) * 32768 + aOff;                             \
    const char* Bb_ = ldsB + (p) * 32768 + bOff;                             \
    bf16x8 fB_[2][4], fA_[4][4];                                             \
    _Pragma("unroll")                                                        \
    for (int n_ = 0; n_ < 2; ++n_)                                           \
        _Pragma("unroll")                                                    \
        for (int ks_ = 0; ks_ < 4; ++ks_)                                    \
            fB_[n_][ks_] = *(const bf16x8*)(Bb_ + n_ * 4096 + ks_ * 1024);   \
    _Pragma("unroll")                                                        \
    for (int m_ = 0; m_ < 4; ++m_)                                           \
        _Pragma("unroll")                                                    \
        for (int ks_ = 0; ks_ < 2; ++ks_)                                    \
            fA_[m_][ks_] = *(const bf16x8*)(Ab_ + m_ * 4096 + ks_ * 1024);   \
    PRIO(1);                                                                 \
    _Pragma("unroll")                                                        \
    for (int ks_ = 0; ks_ < 2; ++ks_)                                        \
        _Pragma("unroll")                                                    \
        for (int m_ = 0; m_ < 4; ++m_)                                       \
            _Pragma("unroll")                                                \
            for (int n_ = 0; n_ < 2; ++n_)                                   \
                acc[m_][n_] = MFMA32(fA_[m_][ks_], fB_[n_][ks_], acc[m_][n_]);\
    PRIO(0);                                                                 \
    _Pragma("unroll")                                                        \
    for (int m_ = 0; m_ < 4; ++m_)                                           \
        _Pragma("unroll")                                                    \
        for (int ks_ = 2; ks_ < 4; ++ks_)                                    \
            fA_[m_][ks_] = *(const bf16x8*)(Ab_ + m_ * 4096 + ks_ * 1024);   \
    SCHEDB();                                                                \
    STG;                                                                     \
    SCHEDB();                                                                \
    PRIO(1);                                                                 \
    _Pragma("unroll")                                                        \
    for (int ks_ = 2; ks_ < 4; ++ks_)                                        \
        _Pragma("unroll")                                                    \
        for (int m_ = 0; m_ < 4; ++m_)                                       \
            _Pragma("unroll")                                                \
            for (int n_ = 0; n_ < 2; ++n_)                                   \
                acc[m_][n_] = MFMA32(fA_[m_][ks_], fB_[n_][ks_], acc[m_][n_]);\
    PRIO(0);                                                                 \
} while (0)

__global__ __launch_bounds__(512, 2) void gemm256_kernel(
    const unsigned short* __restrict__ Abf, const unsigned short* __restrict__ BT,
    float* __restrict__ C)
{
    __shared__ __align__(16) unsigned short As[2][16384];   // 2 x 32 KB
    __shared__ __align__(16) unsigned short Bs[2][16384];   // 2 x 32 KB

    const int tid = threadIdx.x;

    // XCD-bijective chunked swizzle: 256 wgs, 8 XCDs, 32 wgs/XCD.
    const int wg    = blockIdx.x;
    const int lin   = ((wg & 7) << 5) | (wg >> 3);
    const int batch = lin >> 6;
    const int rem   = lin & 63;
    const int row0  = (rem >> 3) * 256;
    const int col0  = (rem & 7) * 256;

    const unsigned short* __restrict__ Abase =
        Abf + (size_t)batch * MD * KD + (size_t)row0 * KD;
    const unsigned short* __restrict__ Bbase =
        BT  + (size_t)batch * ND * KD + (size_t)col0 * KD;
    float* __restrict__ Cbase =
        C + (size_t)batch * MD * ND + (size_t)row0 * ND + col0;

    const int wave = tid >> 6;
    const int lane = tid & 63;
    const int l31  = lane & 31;          // row within 32x32 frag
    const int hi   = lane >> 5;          // k-half selector
    const int wm   = (wave >> 2) * 128;  // 0 / 128
    const int wn   = (wave & 3)  * 64;   // 0,64,128,192

    // staging source decomposition (dest o = rr*8192 + tid*16 bytes):
    //   blk = rr*2 + (tid>>8); ks = (tid>>6)&3; hi = (tid>>5)&1; l31 = tid&31
    //   row = blk*32 + l31;    k = ks*16 + hi*8  (16 B contiguous load)
    const int sRowB = ((tid >> 8) << 5) | (tid & 31);          // + rr*64
    const int sK    = (((tid >> 6) & 3) << 4) | (((tid >> 5) & 1) << 3);

    // fragment-major read bases (everything else folds into immediates)
    const int aOff = ((wave >> 2) * 4) * 4096 + lane * 16;     // + m*4096 + ks*1024
    const int bOff = ((wave & 3) * 2) * 4096 + lane * 16;      // + n*4096 + ks*1024

    const char* ldsA = (const char*)&As[0][0];
    const char* ldsB = (const char*)&Bs[0][0];

    f32x16 acc[4][2];
    #pragma unroll
    for (int m = 0; m < 4; ++m)
        #pragma unroll
        for (int n = 0; n < 2; ++n)
            acc[m][n] = (f32x16){0.f};

    // prologue: stage tile 0 into buf 0
    STAGE4(As, 0, Abase, 0);
    STAGE4(Bs, 0, Bbase, 0);

    for (int j = 0; j < 15; ++j) {       // tiles t=2j, 2j+1 (t <= 29)
        PHASE(0, { STAGE4(As, 1, Abase, 2 * j + 1); STAGE4(Bs, 1, Bbase, 2 * j + 1); });
        PHASE(1, { STAGE4(As, 0, Abase, 2 * j + 2); STAGE4(Bs, 0, Bbase, 2 * j + 2); });
    }
    PHASE(0, { STAGE4(As, 1, Abase, 31); STAGE4(Bs, 1, Bbase, 31); });   // t=30
    PHASE(1, NOSTG);                                                      // t=31

    // epilogue: 32x32 C/D layout col=lane&31, row=(reg&3)+8*(reg>>2)+4*hi
    #pragma unroll
    for (int m = 0; m < 4; ++m)
        #pragma unroll
        for (int n = 0; n < 2; ++n)
            #pragma unroll
            for (int rg = 0; rg < 16; ++rg) {
                const int row = wm + m * 32 + (rg & 3) + 8 * (rg >> 2) + 4 * hi;
                const int col = wn + n * 32 + l31;
                Cbase[(size_t)row * ND + col] = acc[m][n][rg];
            }
}

// ---- Fallback (ws too small): fused fp32-staging kernel ----
#define LSTR 40
__global__ __launch_bounds__(256, 4) void fused_kernel(
    const float* __restrict__ A, const float* __restrict__ Bmat,
    float* __restrict__ C)
{
    __shared__ unsigned short Asf[BM][LSTR];
    __shared__ unsigned short Bsf[BN][LSTR];
    const int tid   = threadIdx.x;
    const int batch = blockIdx.z;
    const int row0  = blockIdx.y * BM;
    const int col0  = blockIdx.x * BN;
    const float* Abase = A    + (size_t)batch * MD * KD + (size_t)row0 * KD;
    const float* Bbase = Bmat + (size_t)batch * KD * ND + col0;
    float*       Cbase = C    + (size_t)batch * MD * ND + (size_t)row0 * ND + col0;
    const int a_row = tid >> 3, a_kc = (tid & 7) * 4;
    const int b_n = tid & 127, b_kh = (tid >> 7) * 16;
    const float* Bcol = Bbase + b_n;
    const int wave = tid >> 6, lane = tid & 63, q = lane >> 4, r = lane & 15;
    const int wm = (wave >> 1) * 64, wn = (wave & 1) * 64;
    f32x4 acc[4][4];
    #pragma unroll
    for (int i = 0; i < 4; ++i)
        #pragma unroll
        for (int j = 0; j < 4; ++j) acc[i][j] = (f32x4){0.f, 0.f, 0.f, 0.f};
    for (int k0 = 0; k0 < KD; k0 += 32) {
        #pragma unroll
        for (int i = 0; i < 4; ++i) {
            const int row = a_row + i * 32;
            const float4 v = *(const float4*)(Abase + (size_t)row * KD + k0 + a_kc);
            uint2 w; w.x = pk2(v.x, v.y); w.y = pk2(v.z, v.w);
            *(uint2*)&Asf[row][a_kc] = w;
        }
        #pragma unroll
        for (int h = 0; h < 2; ++h) {
            const int kb = b_kh + h * 8;
            float bv[8];
            #pragma unroll
            for (int j = 0; j < 8; ++j) bv[j] = Bcol[(size_t)(k0 + kb + j) * ND];
            uint4 w;
            w.x = pk2(bv[0], bv[1]); w.y = pk2(bv[2], bv[3]);
            w.z = pk2(bv[4], bv[5]); w.w = pk2(bv[6], bv[7]);
            *(uint4*)&Bsf[b_n][kb] = w;
        }
        __syncthreads();
        bf16x8 a_frag[4], b_frag[4];
        #pragma unroll
        for (int im = 0; im < 4; ++im)
            a_frag[im] = *(const bf16x8*)&Asf[wm + im * 16 + r][q * 8];
        #pragma unroll
        for (int in = 0; in < 4; ++in)
            b_frag[in] = *(const bf16x8*)&Bsf[wn + in * 16 + r][q * 8];
        #pragma unroll
        for (int im = 0; im < 4; ++im)
            #pragma unroll
            for (int in = 0; in < 4; ++in)
                acc[im][in] = MFMA16(a_frag[im], b_frag[in], acc[im][in]);
        __syncthreads();
    }
    #pragma unroll
    for (int im = 0; im < 4; ++im)
        #pragma unroll
        for (int in = 0; in < 4; ++in)
            #pragma unroll
            for (int j = 0; j < 4; ++j)
                Cbase[(size_t)(wm + im * 16 + q * 4 + j) * ND + wn + in * 16 + r]
                    = acc[im][in][j];
}

extern "C" void kernel_launch(void* const* d_in, const int* in_sizes, int n_in,
                              void* d_out, int out_size, void* d_ws, size_t ws_size,
                              hipStream_t stream) {
    const float* a = (const float*)d_in[0];
    const float* b = (const float*)d_in[1];
    float* out = (float*)d_out;

    const size_t abf_bytes = (size_t)NB * MD * KD * 2;   // 32 MB
    const size_t bt_bytes  = (size_t)NB * KD * ND * 2;   // 32 MB

    if (ws_size >= abf_bytes + bt_bytes) {
        unsigned short* Abf = (unsigned short*)d_ws;
        unsigned short* BT  = (unsigned short*)((char*)d_ws + abf_bytes);
        prep_kernel<<<dim3(NCAST + NB * (KD / 64) * (ND / 64)), dim3(256), 0, stream>>>(
            a, b, Abf, BT);
        const int nwg = (MD / 256) * (ND / 256) * NB;    // 256
        gemm256_kernel<<<dim3(nwg), dim3(512), 0, stream>>>(Abf, BT, out);
    } else {
        fused_kernel<<<dim3(ND / BN, MD / BM, NB), dim3(256), 0, stream>>>(a, b, out);
    }
}